// Round 6
// baseline (340.647 us; speedup 1.0000x reference)
//
#include <hip/hip_runtime.h>
#include <hip/hip_bf16.h>
#include <stddef.h>

// Correlation cost volume via bf16 MFMA band-matmul — BARRIER-FREE direct-
// fragment design.
// out[b, di*9+dj, h, w] = (1/256) * sum_c x1[b,c,h,w] * x2[b,c,h+di-4,w+dj-4]
// B=4, C=256, H=96, W=192.
//
// R6 rationale: R2-R5 (LDS-staged, per-chunk block barriers) sat at 130-155us
// with ALL pipes idle -> bound by the serial barrier skeleton, not any pipe.
// R6 removes it: each wave loads its own B-fragments per-lane from global
// (L1/L2-served, 4x64B segments per instr), software-pipelined 1 step ahead,
// A double-buffered per chunk, no LDS/barriers until the epilogue transpose
// (which is intra-wave only -> still no s_barrier).

#define NB 4
#define NC 256
#define HH 96
#define WW 192
#define CHW (HH * WW)      // 18432
#define TW 16
#define TH 4
#define KC 32

typedef __attribute__((ext_vector_type(8))) short bf16x8;
typedef __attribute__((ext_vector_type(4))) float f32x4;

union Frag { unsigned long long u[2]; unsigned int w[4]; bf16x8 v; };

__device__ __forceinline__ unsigned int pk2(float a, float b) {
    __hip_bfloat162 t = __float22bfloat162_rn(make_float2(a, b));
    union { __hip_bfloat162 h; unsigned int u; } c; c.h = t; return c.u;
}

__global__ __launch_bounds__(256, 3) void corr_direct(
    const float* __restrict__ x1, const float* __restrict__ x2,
    float* __restrict__ out)
{
    __shared__ float band[TH][9][9][18];   // 23328 B, intra-wave transpose only

    const int tid  = threadIdx.x;
    const int wv   = tid >> 6;        // wave 0..3 -> h row
    const int lane = tid & 63;
    const int col  = lane & 15;
    const int q    = lane >> 4;
    const int w0   = blockIdx.x * TW;
    const int h0   = blockIdx.y * TH;
    const int b    = blockIdx.z;
    const int h    = h0 + wv;

    const float* x1b = x1 + (size_t)b * NC * CHW;
    const float* x2b = x2 + (size_t)b * NC * CHW;

    // Per-lane constant element offsets for B loads (include clamped abs col).
    const int ac0  = w0 - 4 + col;        // half0 absolute x2 col
    const int ac1  = ac0 + 16;            // half1
    const bool okw0 = (ac0 >= 0) & (ac0 < WW);
    const bool okw1 = (ac1 >= 0) & (ac1 < WW);
    const int cl0 = ac0 < 0 ? 0 : (ac0 > WW - 1 ? WW - 1 : ac0);
    const int cl1 = ac1 < 0 ? 0 : (ac1 > WW - 1 ? WW - 1 : ac1);
    int voffB0[8], voffB1[8];
#pragma unroll
    for (int j = 0; j < 8; ++j) {
        voffB0[j] = (q * 8 + j) * CHW + cl0;
        voffB1[j] = (q * 8 + j) * CHW + cl1;
    }
    const int voffA = (q * 8) * CHW + col;

    f32x4 acc[9][2];
#pragma unroll
    for (int di = 0; di < 9; ++di) {
        acc[di][0] = (f32x4)0.0f;
        acc[di][1] = (f32x4)0.0f;
    }

    float pb[2][16];      // ping-pong B raw-f32 buffer (1 step ahead)
    float pa0[8], pa1[8]; // double-buffered A raw-f32 (per chunk)

    // Scalar (readfirstlane) base + per-lane const offsets -> saddr-form loads.
#define ISSUE_B(KCH_, DI_, DST)                                                \
    {                                                                          \
        int row_ = h + (DI_) - 4;                                              \
        row_ = row_ < 0 ? 0 : (row_ > HH - 1 ? HH - 1 : row_);                 \
        int sb_ = __builtin_amdgcn_readfirstlane((KCH_) * CHW + row_ * WW);    \
        const float* p_ = x2b + sb_;                                           \
        _Pragma("unroll")                                                      \
        for (int j_ = 0; j_ < 8; ++j_) (DST)[j_] = p_[voffB0[j_]];             \
        _Pragma("unroll")                                                      \
        for (int j_ = 0; j_ < 8; ++j_) (DST)[8 + j_] = p_[voffB1[j_]];         \
    }

#define ISSUE_A(KCH_, DST)                                                     \
    {                                                                          \
        int sb_ = __builtin_amdgcn_readfirstlane((KCH_) * CHW + h * WW + w0);  \
        const float* p_ = x1b + sb_;                                           \
        _Pragma("unroll")                                                      \
        for (int j_ = 0; j_ < 8; ++j_) (DST)[j_] = p_[voffA + j_ * CHW];       \
    }

    // Mask edge cols, pack to bf16, 2 MFMAs. Skip entirely for out-of-image
    // rows (wave-uniform branch; zero-pad contribution is zero).
#define PROC(DI_, PB_, FA_)                                                    \
    {                                                                          \
        int row_ = h + (DI_) - 4;                                              \
        if ((unsigned)row_ < (unsigned)HH) {                                   \
            Frag b0_, b1_;                                                     \
            _Pragma("unroll")                                                  \
            for (int jj_ = 0; jj_ < 4; ++jj_) {                                \
                float u0_ = okw0 ? (PB_)[2 * jj_]     : 0.0f;                  \
                float u1_ = okw0 ? (PB_)[2 * jj_ + 1] : 0.0f;                  \
                b0_.w[jj_] = pk2(u0_, u1_);                                    \
                float v0_ = okw1 ? (PB_)[8 + 2 * jj_]     : 0.0f;              \
                float v1_ = okw1 ? (PB_)[8 + 2 * jj_ + 1] : 0.0f;              \
                b1_.w[jj_] = pk2(v0_, v1_);                                    \
            }                                                                  \
            acc[DI_][0] = __builtin_amdgcn_mfma_f32_16x16x32_bf16(             \
                (FA_).v, b0_.v, acc[DI_][0], 0, 0, 0);                         \
            acc[DI_][1] = __builtin_amdgcn_mfma_f32_16x16x32_bf16(             \
                (FA_).v, b1_.v, acc[DI_][1], 0, 0, 0);                         \
        }                                                                      \
    }

    // Prologue: step 0 loads + chunk-0 A.
    ISSUE_A(0, pa0)
    ISSUE_B(0, 0, pb[0])

    Frag fa;
#pragma unroll 1
    for (int cc = 0; cc < 4; ++cc) {
        const int c0 = cc * 2;            // even -> chunk parity == lc
#pragma unroll
        for (int t = 0; t < 18; ++t) {
            const int lc  = t / 9;        // local chunk 0/1 (compile-time)
            const int di  = t % 9;
            const int par = t & 1;

            if (di == 0) {                // pack this chunk's A-frag
                const float* pav = (lc == 0) ? pa0 : pa1;
#pragma unroll
                for (int jj = 0; jj < 4; ++jj)
                    fa.w[jj] = pk2(pav[2 * jj], pav[2 * jj + 1]);
            }

            // Issue next step's B loads (clamped past the end: harmless reload).
            {
                const int tn = t + 1, lcn = tn / 9, din = tn % 9;
                int kn = c0 + lcn; if (kn > 7) kn = 7;
                ISSUE_B(kn * KC, din, pb[1 - par])
            }
            if (di == 4) {                // prefetch next chunk's A mid-chunk
                int an = c0 + lc + 1; if (an > 7) an = 7;
                if (lc == 0) { ISSUE_A(an * KC, pa1) }
                else         { ISSUE_A(an * KC, pa0) }
            }

            PROC(di, pb[par], fa)
        }
    }

    // ---- epilogue: band extraction P[m, m+dj] -> band[wv][di][dj][m].
    // D layout: n = lane&15, m = q*4 + reg. Intra-wave only (each wave reads
    // its own band[wv] slice) -> no s_barrier needed; lgkmcnt orders RAW.
#pragma unroll
    for (int di = 0; di < 9; ++di)
#pragma unroll
        for (int half = 0; half < 2; ++half)
#pragma unroll
            for (int r = 0; r < 4; ++r) {
                int m  = q * 4 + r;
                int dj = half * 16 + col - m;
                if (dj >= 0 && dj < 9)
                    band[wv][di][dj][m] = acc[di][half][r];
            }

    const float scale = 1.0f / 256.0f;
#pragma unroll
    for (int it = 0; it < 21; ++it) {
        int combo = it * 4 + q;           // di*9+dj
        if (combo < 81) {
            float v = band[wv][combo / 9][combo % 9][col];
            out[((size_t)((b * 81 + combo) * HH + h)) * WW + w0 + col] = v * scale;
        }
    }
}

extern "C" void kernel_launch(void* const* d_in, const int* in_sizes, int n_in,
                              void* d_out, int out_size, void* d_ws, size_t ws_size,
                              hipStream_t stream) {
    const float* x1 = (const float*)d_in[0];
    const float* x2 = (const float*)d_in[1];
    float* out = (float*)d_out;

    dim3 grid(WW / TW, HH / TH, NB);   // 12 x 24 x 4 = 1152 blocks, 256 thr
    corr_direct<<<grid, 256, 0, stream>>>(x1, x2, out);
}